// Round 3
// baseline (335.154 us; speedup 1.0000x reference)
//
#include <hip/hip_runtime.h>

namespace {
constexpr int HD  = 128;
constexpr int NH  = 32;
constexpr int NKV = 8;
constexpr int SEQ = 8192;
constexpr int ROW = NH * HD + 2 * NKV * HD;          // 6144 floats per qkv row
constexpr int QK_HEADS = NH + NKV;                   // 40 heads, contiguous per row
constexpr int WAVES_PER_TOKEN = QK_HEADS / 4;        // 10 (4 heads per wave, 2 pairs)
constexpr int QK_WAVES  = SEQ * WAVES_PER_TOKEN;     // 81920
constexpr int QK_BLOCKS = QK_WAVES / 4;              // 20480 (4 waves/block)
constexpr long long Q_OUT = (long long)SEQ * NH * HD;    // 33554432 floats
constexpr long long K_OUT = (long long)SEQ * NKV * HD;   //  8388608 floats
constexpr long long V_OFF = Q_OUT + K_OUT;
constexpr int V_ROW = NKV * HD;                      // 1024 floats of V per token
constexpr int V_TOK_PER_BLOCK = 4;                   // one token row per 256-thread pass
constexpr int V_BLOCKS = SEQ / V_TOK_PER_BLOCK;      // 2048
constexpr float EPS = 1e-6f;
}

// Blocks [0, QK_BLOCKS): q/k rmsnorm + rope. Each 64-lane wave processes 4
// consecutive heads (two head-pairs) of one token; lane = float4 (16B). Both
// HBM loads are issued before the two independent 32-lane shuffle-reduce
// chains run interleaved (2 loads in flight, DS latency overlapped).
// Head-groups of 4 never straddle the q/k boundary (32 % 4 == 0).
// Rotate-half partner (d +/- 64) is lane^16 -> one shuffle, fp32 end-to-end.
// Blocks [QK_BLOCKS, QK_BLOCKS+V_BLOCKS): v copy, 4 float4/thread
// (load-all-then-store-all), one full token V-row per 256-thread pass.
__global__ __launch_bounds__(256) void qknorm_rope_kernel(
    const float* __restrict__ qkv,
    const float* __restrict__ qw,
    const float* __restrict__ kw,
    const float* __restrict__ cw,
    const float* __restrict__ sw,
    float* __restrict__ out)
{
    const int bid = blockIdx.x;
    const int tid = threadIdx.x;

    if (bid < QK_BLOCKS) {
        const int lane = tid & 63;
        const int W    = bid * 4 + (tid >> 6);      // global wave id
        const int t    = W / WAVES_PER_TOKEN;       // token
        const int jg   = W - t * WAVES_PER_TOKEN;   // head-quad index (0..9)
        const int h0   = jg * 4 + (lane >> 5);      // pair-0 head
        const int h1   = h0 + 2;                    // pair-1 head
        const int d0   = (lane & 31) * 4;           // element base in head dim
        const float* base = qkv + (long long)t * ROW;

        const float4 xa4 = *(const float4*)(base + h0 * HD + d0);
        const float4 xb4 = *(const float4*)(base + h1 * HD + d0);
        const float xa[4] = {xa4.x, xa4.y, xa4.z, xa4.w};
        const float xb[4] = {xb4.x, xb4.y, xb4.z, xb4.w};

        float ssa = 0.f, ssb = 0.f;
        #pragma unroll
        for (int i = 0; i < 4; ++i) { ssa += xa[i] * xa[i]; ssb += xb[i] * xb[i]; }
        #pragma unroll
        for (int m = 1; m < 32; m <<= 1) {
            ssa += __shfl_xor(ssa, m, 64);
            ssb += __shfl_xor(ssb, m, 64);
        }
        const float inva = rsqrtf(ssa * (1.0f / HD) + EPS);
        const float invb = rsqrtf(ssb * (1.0f / HD) + EPS);

        const float* wp = (h0 < NH) ? qw : kw;      // whole quad is q or k
        const float4 w4 = *(const float4*)(wp + d0);
        const float4 c4 = *(const float4*)(cw + d0);
        const float4 s4 = *(const float4*)(sw + d0);
        const float w[4] = {w4.x, w4.y, w4.z, w4.w};
        const float c[4] = {c4.x, c4.y, c4.z, c4.w};
        const float s[4] = {s4.x, s4.y, s4.z, s4.w};

        float qa[4], qb[4];
        #pragma unroll
        for (int i = 0; i < 4; ++i) {
            qa[i] = xa[i] * inva * w[i];
            qb[i] = xb[i] * invb * w[i];
        }

        // d = d0 + i. (lane&16)==0 -> d<64 -> out = qn*cos - qn[d+64]*sin
        //             (lane&16)!=0 -> d>=64 -> out = qn*cos + qn[d-64]*sin
        const float sign = (lane & 16) ? 1.0f : -1.0f;
        float4 oa, ob;
        float* oap = &oa.x; float* obp = &ob.x;
        #pragma unroll
        for (int i = 0; i < 4; ++i) {
            const float ra = __shfl_xor(qa[i], 16, 64);
            const float rb = __shfl_xor(qb[i], 16, 64);
            oap[i] = qa[i] * c[i] + sign * ra * s[i];
            obp[i] = qb[i] * c[i] + sign * rb * s[i];
        }

        long long dst0, dst1;
        if (h0 < NH) {
            dst0 = (long long)t * (NH * HD) + h0 * HD + d0;
            dst1 = (long long)t * (NH * HD) + h1 * HD + d0;
        } else {
            dst0 = Q_OUT + (long long)t * (NKV * HD) + (h0 - NH) * HD + d0;
            dst1 = Q_OUT + (long long)t * (NKV * HD) + (h1 - NH) * HD + d0;
        }
        *(float4*)(out + dst0) = oa;
        *(float4*)(out + dst1) = ob;
    } else {
        // v copy: token row = 1024 floats = 256 float4 chunks = one pass
        const int t0 = (bid - QK_BLOCKS) * V_TOK_PER_BLOCK;
        float4 v[V_TOK_PER_BLOCK];
        #pragma unroll
        for (int u = 0; u < V_TOK_PER_BLOCK; ++u) {
            const int t = t0 + u;
            v[u] = *(const float4*)(qkv + (long long)t * ROW + QK_HEADS * HD + tid * 4);
        }
        #pragma unroll
        for (int u = 0; u < V_TOK_PER_BLOCK; ++u) {
            const int t = t0 + u;
            *(float4*)(out + V_OFF + (long long)t * V_ROW + tid * 4) = v[u];
        }
    }
}

extern "C" void kernel_launch(void* const* d_in, const int* in_sizes, int n_in,
                              void* d_out, int out_size, void* d_ws, size_t ws_size,
                              hipStream_t stream) {
    const float* qkv = (const float*)d_in[0];
    const float* qw  = (const float*)d_in[1];
    const float* kw  = (const float*)d_in[2];
    const float* cw  = (const float*)d_in[3];
    const float* sw  = (const float*)d_in[4];
    float* out = (float*)d_out;

    qknorm_rope_kernel<<<QK_BLOCKS + V_BLOCKS, 256, 0, stream>>>(qkv, qw, kw, cw, sw, out);
}